// Round 1
// baseline (5362.176 us; speedup 1.0000x reference)
//
#include <hip/hip_runtime.h>
#include <stdint.h>

#define H 64
#define DIN 275
#define DINP 288
#define AHEAD 14

// ---------- small prep kernels ----------
__global__ void k_pad_encw(const float* __restrict__ w, float* __restrict__ wp) {
  int i = blockIdx.x * 256 + threadIdx.x;
  if (i >= 64 * DINP) return;
  int f = i / DINP, k = i % DINP;
  wp[i] = (k < DIN) ? w[f * DIN + k] : 0.f;
}

__global__ void k_init_deg(int* __restrict__ deg, int n) {
  int i = blockIdx.x * 256 + threadIdx.x;
  if (i < n) deg[i] = 1;  // self-loop
}

__global__ void k_deg(const int* __restrict__ dst, int* __restrict__ deg, int e) {
  int i = blockIdx.x * 256 + threadIdx.x;
  if (i < e) atomicAdd(&deg[dst[i]], 1);
}

// ---------- 2-level exclusive scan over deg -> row_start ----------
__global__ void k_scan1(const int* __restrict__ in, int* __restrict__ part,
                        int* __restrict__ bsums, int n) {
  int tid = threadIdx.x;
  int gid = blockIdx.x * 256 + tid;
  int v = (gid < n) ? in[gid] : 0;
  int lane = tid & 63, wv = tid >> 6;
  int x = v;
#pragma unroll
  for (int d = 1; d < 64; d <<= 1) {
    int y = __shfl_up(x, d, 64);
    if (lane >= d) x += y;
  }
  __shared__ int ws_[4];
  if (lane == 63) ws_[wv] = x;
  __syncthreads();
  int off = 0;
  for (int i = 0; i < wv; ++i) off += ws_[i];
  int incl = x + off;
  if (gid < n) part[gid] = incl - v;
  if (tid == 255) bsums[blockIdx.x] = incl;
}

__global__ void k_scan2(int* __restrict__ bsums, int nb) {
  int tid = threadIdx.x;  // block of 1024, nb <= 1024
  int v = (tid < nb) ? bsums[tid] : 0;
  int lane = tid & 63, wv = tid >> 6;
  int x = v;
#pragma unroll
  for (int d = 1; d < 64; d <<= 1) {
    int y = __shfl_up(x, d, 64);
    if (lane >= d) x += y;
  }
  __shared__ int ws_[16];
  if (lane == 63) ws_[wv] = x;
  __syncthreads();
  int off = 0;
  for (int i = 0; i < wv; ++i) off += ws_[i];
  int incl = x + off;
  if (tid < nb) bsums[tid] = incl - v;  // exclusive block offsets
}

__global__ void k_scanfin(const int* __restrict__ part, const int* __restrict__ bsums,
                          const int* __restrict__ deg, int* __restrict__ row_start,
                          int* __restrict__ cursor, float* __restrict__ dis,
                          int n, int total) {
  int gid = blockIdx.x * 256 + threadIdx.x;
  if (gid < n) {
    int rs = part[gid] + bsums[gid >> 8];
    row_start[gid] = rs;
    cursor[gid] = rs;
    dis[gid] = rsqrtf((float)deg[gid]);  // deg >= 1 always (self-loop)
  } else if (gid == n) {
    row_start[n] = total;
  }
}

__global__ void k_fill(const int* __restrict__ src, const int* __restrict__ dst,
                       int* __restrict__ cursor, int* __restrict__ csr, int e, int n) {
  int i = blockIdx.x * 256 + threadIdx.x;
  if (i >= e + n) return;
  int s, d;
  if (i < e) { s = src[i]; d = dst[i]; }
  else       { s = i - e; d = s; }      // self loops
  int pos = atomicAdd(&cursor[d], 1);
  csr[pos] = s;
}

// ---------- fused encoder + GRU: lane = node, wave-uniform weights via s_load ----------
__global__ __launch_bounds__(256, 3) void k_encgru(
    const float* __restrict__ inp, const float* __restrict__ hid,
    const float* __restrict__ wenc, const float* __restrict__ benc,
    const float* __restrict__ wih, const float* __restrict__ whh,
    const float* __restrict__ bih, const float* __restrict__ bhh,
    float* __restrict__ h2o, int n) {
  __shared__ float X[4][64 * 33];  // per-wave tile, pad 33 -> 2-way bank alias (free)
  int tid = threadIdx.x;
  int wv = tid >> 6, lane = tid & 63;
  long long group = (long long)blockIdx.x * 4 + wv;
  long long node0 = group * 64;
  if (node0 >= n) node0 = 0;  // dead group recomputes node 0..63; stores masked
  float* Xw = X[wv];

  float h1[64];
#pragma unroll
  for (int f = 0; f < 64; ++f) h1[f] = benc[f];

  for (int kc = 0; kc < DINP; kc += 32) {
    // stage 64 rows x 32 cols (coalesced: 2 rows per iteration)
#pragma unroll
    for (int r2 = 0; r2 < 32; ++r2) {
      int row = r2 * 2 + (lane >> 5);
      int col = lane & 31;
      int k = kc + col;
      long long nd = node0 + row;
      float v = 0.f;
      if (k < DIN && nd < n) v = inp[nd * DIN + k];
      Xw[row * 33 + col] = v;
    }
    __syncthreads();
    float xr[32];
#pragma unroll
    for (int kk = 0; kk < 32; ++kk) xr[kk] = Xw[lane * 33 + kk];
    const float* wp = wenc + kc;
#pragma unroll
    for (int f = 0; f < 64; ++f) {
#pragma unroll
      for (int kk = 0; kk < 32; ++kk)
        h1[f] = fmaf(wp[f * DINP + kk], xr[kk], h1[f]);  // weight is s_load (uniform)
    }
    __syncthreads();
  }
#pragma unroll
  for (int f = 0; f < 64; ++f) h1[f] = fmaxf(h1[f], 0.f);

  long long nodeBase = group * 64;
  long long nodeL = nodeBase + lane;
  bool valid = nodeL < n;
  long long nodeC = valid ? nodeL : 0;

  float hin[64];
  const float4* hp = (const float4*)(hid + nodeC * 64);
#pragma unroll
  for (int q = 0; q < 16; ++q) {
    float4 t = hp[q];
    hin[q * 4 + 0] = t.x; hin[q * 4 + 1] = t.y;
    hin[q * 4 + 2] = t.z; hin[q * 4 + 3] = t.w;
  }

  for (int f = 0; f < 64; ++f) {  // rolled: 6 live accumulators
    float ir = bih[f], iz = bih[64 + f], inn = bih[128 + f];
    float hrr = bhh[f], hz = bhh[64 + f], hn = bhh[128 + f];
    const float* wi0 = wih + f * 64;
    const float* wi1 = wih + (64 + f) * 64;
    const float* wi2 = wih + (128 + f) * 64;
    const float* wh0 = whh + f * 64;
    const float* wh1 = whh + (64 + f) * 64;
    const float* wh2 = whh + (128 + f) * 64;
#pragma unroll
    for (int k = 0; k < 64; ++k) {
      float a = h1[k], b = hin[k];
      ir  = fmaf(wi0[k], a, ir);
      iz  = fmaf(wi1[k], a, iz);
      inn = fmaf(wi2[k], a, inn);
      hrr = fmaf(wh0[k], b, hrr);
      hz  = fmaf(wh1[k], b, hz);
      hn  = fmaf(wh2[k], b, hn);
    }
    float r = 1.f / (1.f + __expf(-(ir + hrr)));
    float z = 1.f / (1.f + __expf(-(iz + hz)));
    float nn = tanhf(inn + r * hn);
    float hf = hid[nodeC * 64 + f];  // reload (L1-hot) to avoid dyn reg indexing
    float h2 = (1.f - z) * nn + z * hf;
    if (valid) h2o[nodeL * 64 + f] = h2;
  }
}

// ---------- y = x @ W^T, W [64][64] row-major; thread = node ----------
__global__ void k_gemv64(const float* __restrict__ x, const float* __restrict__ W,
                         float* __restrict__ y, int n) {
  int node = blockIdx.x * 256 + threadIdx.x;
  if (node >= n) return;
  float xr[64];
  const float4* xp = (const float4*)(x + (size_t)node * 64);
#pragma unroll
  for (int q = 0; q < 16; ++q) {
    float4 t = xp[q];
    xr[q * 4 + 0] = t.x; xr[q * 4 + 1] = t.y;
    xr[q * 4 + 2] = t.z; xr[q * 4 + 3] = t.w;
  }
  float* yo = y + (size_t)node * 64;
#pragma unroll 4
  for (int f = 0; f < 64; ++f) {
    float acc = 0.f;
    const float* wr = W + f * 64;
#pragma unroll
    for (int k = 0; k < 64; ++k) acc = fmaf(wr[k], xr[k], acc);
    yo[f] = acc;
  }
}

// ---------- gather aggregation: wave = dst node, lane = feature ----------
__global__ void k_agg(const float* __restrict__ y, const int* __restrict__ row_start,
                      const int* __restrict__ csr, const float* __restrict__ dis,
                      const float* __restrict__ bias, float* __restrict__ out,
                      int n, int dorelu) {
  int t = blockIdx.x * 256 + threadIdx.x;
  int w = t >> 6;
  int lane = t & 63;
  if (w >= n) return;
  w = __builtin_amdgcn_readfirstlane(w);  // wave-uniform -> scalar path
  int beg = row_start[w], end = row_start[w + 1];
  float acc = 0.f;
  int i = beg;
  for (; i + 4 <= end; i += 4) {
    int s0 = csr[i], s1 = csr[i + 1], s2 = csr[i + 2], s3 = csr[i + 3];
    float n0 = dis[s0], n1 = dis[s1], n2 = dis[s2], n3 = dis[s3];
    float v0 = y[(size_t)s0 * 64 + lane];
    float v1 = y[(size_t)s1 * 64 + lane];
    float v2 = y[(size_t)s2 * 64 + lane];
    float v3 = y[(size_t)s3 * 64 + lane];
    acc += v0 * n0 + v1 * n1 + v2 * n2 + v3 * n3;
  }
  for (; i < end; ++i) {
    int s = csr[i];
    acc += y[(size_t)s * 64 + lane] * dis[s];
  }
  acc = acc * dis[w] + bias[lane];
  if (dorelu) acc = fmaxf(acc, 0.f);
  out[(size_t)w * 64 + lane] = acc;
}

// ---------- Q head ----------
__global__ void k_qhead(const float* __restrict__ h3, const float* __restrict__ qw,
                        const float* __restrict__ qb, float* __restrict__ qout, int n) {
  int node = blockIdx.x * 256 + threadIdx.x;
  if (node >= n) return;
  float xr[64];
  const float4* xp = (const float4*)(h3 + (size_t)node * 64);
#pragma unroll
  for (int q = 0; q < 16; ++q) {
    float4 t = xp[q];
    xr[q * 4 + 0] = t.x; xr[q * 4 + 1] = t.y;
    xr[q * 4 + 2] = t.z; xr[q * 4 + 3] = t.w;
  }
  float* qo = qout + (size_t)node * AHEAD;
#pragma unroll 2
  for (int a = 0; a < AHEAD; ++a) {
    float acc = qb[a];
    const float* wr = qw + a * 64;
#pragma unroll
    for (int k = 0; k < 64; ++k) acc = fmaf(wr[k], xr[k], acc);
    qo[a] = acc;
  }
}

extern "C" void kernel_launch(void* const* d_in, const int* in_sizes, int n_in,
                              void* d_out, int out_size, void* d_ws, size_t ws_size,
                              hipStream_t stream) {
  const float* inp  = (const float*)d_in[0];
  const float* hid  = (const float*)d_in[1];
  const int*   eidx = (const int*)d_in[2];
  const float* encw = (const float*)d_in[3];
  const float* encb = (const float*)d_in[4];
  const float* wih  = (const float*)d_in[5];
  const float* whh  = (const float*)d_in[6];
  const float* bih  = (const float*)d_in[7];
  const float* bhh  = (const float*)d_in[8];
  const float* g1w  = (const float*)d_in[9];
  const float* g1b  = (const float*)d_in[10];
  const float* g2w  = (const float*)d_in[11];
  const float* g2b  = (const float*)d_in[12];
  const float* qw   = (const float*)d_in[13];
  const float* qb   = (const float*)d_in[14];

  int n = in_sizes[1] / H;   // 200000
  int e = in_sizes[2] / 2;   // 3200000
  const int* esrc = eidx;
  const int* edst = eidx + e;

  float* qout = (float*)d_out;
  float* h2o  = (float*)d_out + (size_t)n * AHEAD;

  // workspace carve (~120 MB)
  char* w = (char*)d_ws;
  float* wencp   = (float*)w; w += (size_t)64 * DINP * 4;
  int* deg       = (int*)w;   w += (size_t)n * 4;
  int* part      = (int*)w;   w += (size_t)n * 4;
  int* bsums     = (int*)w;   w += 4096;
  int* row_start = (int*)w;   w += ((size_t)n + 1) * 4;
  int* cursor    = (int*)w;   w += (size_t)n * 4;
  float* dis     = (float*)w; w += (size_t)n * 4;
  int* csr       = (int*)w;   w += (size_t)(e + n) * 4;
  w = (char*)(((uintptr_t)w + 15) & ~(uintptr_t)15);
  float* ybuf    = (float*)w; w += (size_t)n * H * 4;
  float* xbuf    = (float*)w; w += (size_t)n * H * 4;

  int nb = (n + 255) / 256;
  int total = e + n;

  hipLaunchKernelGGL(k_pad_encw, dim3((64 * DINP + 255) / 256), dim3(256), 0, stream, encw, wencp);
  hipLaunchKernelGGL(k_init_deg, dim3(nb), dim3(256), 0, stream, deg, n);
  hipLaunchKernelGGL(k_deg, dim3((e + 255) / 256), dim3(256), 0, stream, edst, deg, e);
  hipLaunchKernelGGL(k_scan1, dim3(nb), dim3(256), 0, stream, deg, part, bsums, n);
  hipLaunchKernelGGL(k_scan2, dim3(1), dim3(1024), 0, stream, bsums, nb);
  hipLaunchKernelGGL(k_scanfin, dim3((n + 1 + 255) / 256), dim3(256), 0, stream,
                     part, bsums, deg, row_start, cursor, dis, n, total);
  hipLaunchKernelGGL(k_fill, dim3((total + 255) / 256), dim3(256), 0, stream,
                     esrc, edst, cursor, csr, e, n);

  int groups = (n + 63) / 64;
  hipLaunchKernelGGL(k_encgru, dim3((groups + 3) / 4), dim3(256), 0, stream,
                     inp, hid, wencp, encb, wih, whh, bih, bhh, h2o, n);

  int aggblocks = (int)(((size_t)n * 64 + 255) / 256);
  hipLaunchKernelGGL(k_gemv64, dim3(nb), dim3(256), 0, stream, h2o, g1w, ybuf, n);
  hipLaunchKernelGGL(k_agg, dim3(aggblocks), dim3(256), 0, stream,
                     ybuf, row_start, csr, dis, g1b, xbuf, n, 1);
  hipLaunchKernelGGL(k_gemv64, dim3(nb), dim3(256), 0, stream, xbuf, g2w, ybuf, n);
  hipLaunchKernelGGL(k_agg, dim3(aggblocks), dim3(256), 0, stream,
                     ybuf, row_start, csr, dis, g2b, xbuf, n, 0);
  hipLaunchKernelGGL(k_qhead, dim3(nb), dim3(256), 0, stream, xbuf, qw, qb, qout, n);
}

// Round 2
// 2639.095 us; speedup vs baseline: 2.0318x; 2.0318x over previous
//
#include <hip/hip_runtime.h>
#include <stdint.h>

#define H 64
#define DIN 275
#define DINP 288
#define AHEAD 14

// ---------- small prep kernels ----------
__global__ void k_pad_encw(const float* __restrict__ w, float* __restrict__ wp) {
  int i = blockIdx.x * 256 + threadIdx.x;
  if (i >= 64 * DINP) return;
  int f = i / DINP, k = i % DINP;
  wp[i] = (k < DIN) ? w[f * DIN + k] : 0.f;
}

__global__ void k_init_deg(int* __restrict__ deg, int n) {
  int i = blockIdx.x * 256 + threadIdx.x;
  if (i < n) deg[i] = 1;  // self-loop
}

__global__ void k_deg(const int* __restrict__ dst, int* __restrict__ deg, int e) {
  int i = blockIdx.x * 256 + threadIdx.x;
  if (i < e) atomicAdd(&deg[dst[i]], 1);
}

// ---------- 2-level exclusive scan over deg -> row_start ----------
__global__ void k_scan1(const int* __restrict__ in, int* __restrict__ part,
                        int* __restrict__ bsums, int n) {
  int tid = threadIdx.x;
  int gid = blockIdx.x * 256 + tid;
  int v = (gid < n) ? in[gid] : 0;
  int lane = tid & 63, wv = tid >> 6;
  int x = v;
#pragma unroll
  for (int d = 1; d < 64; d <<= 1) {
    int y = __shfl_up(x, d, 64);
    if (lane >= d) x += y;
  }
  __shared__ int ws_[4];
  if (lane == 63) ws_[wv] = x;
  __syncthreads();
  int off = 0;
  for (int i = 0; i < wv; ++i) off += ws_[i];
  int incl = x + off;
  if (gid < n) part[gid] = incl - v;
  if (tid == 255) bsums[blockIdx.x] = incl;
}

__global__ void k_scan2(int* __restrict__ bsums, int nb) {
  int tid = threadIdx.x;  // block of 1024, nb <= 1024
  int v = (tid < nb) ? bsums[tid] : 0;
  int lane = tid & 63, wv = tid >> 6;
  int x = v;
#pragma unroll
  for (int d = 1; d < 64; d <<= 1) {
    int y = __shfl_up(x, d, 64);
    if (lane >= d) x += y;
  }
  __shared__ int ws_[16];
  if (lane == 63) ws_[wv] = x;
  __syncthreads();
  int off = 0;
  for (int i = 0; i < wv; ++i) off += ws_[i];
  int incl = x + off;
  if (tid < nb) bsums[tid] = incl - v;  // exclusive block offsets
}

__global__ void k_scanfin(const int* __restrict__ part, const int* __restrict__ bsums,
                          const int* __restrict__ deg, int* __restrict__ row_start,
                          int* __restrict__ cursor, float* __restrict__ dis,
                          int n, int total) {
  int gid = blockIdx.x * 256 + threadIdx.x;
  if (gid < n) {
    int rs = part[gid] + bsums[gid >> 8];
    row_start[gid] = rs;
    cursor[gid] = rs;
    dis[gid] = rsqrtf((float)deg[gid]);  // deg >= 1 always (self-loop)
  } else if (gid == n) {
    row_start[n] = total;
  }
}

__global__ void k_fill(const int* __restrict__ src, const int* __restrict__ dst,
                       int* __restrict__ cursor, int* __restrict__ csr, int e, int n) {
  int i = blockIdx.x * 256 + threadIdx.x;
  if (i >= e + n) return;
  int s, d;
  if (i < e) { s = src[i]; d = dst[i]; }
  else       { s = i - e; d = s; }      // self loops
  int pos = atomicAdd(&cursor[d], 1);
  csr[pos] = s;
}

// ---------- encoder: lane = node, wave-uniform weights via s_load ----------
// h1[64] accumulators live in VGPRs; __launch_bounds__(256,2) -> 256 VGPR budget, no spill.
__global__ __launch_bounds__(256, 2) void k_enc(
    const float* __restrict__ inp, const float* __restrict__ wenc,
    const float* __restrict__ benc, float* __restrict__ h1o, int n) {
  __shared__ float X[4][64 * 65];  // per-wave tile (stride 65: odd -> 2-way bank alias, free)
  int tid = threadIdx.x;
  int wv = tid >> 6, lane = tid & 63;
  long long group = (long long)blockIdx.x * 4 + wv;
  long long node0 = group * 64;
  bool dead = node0 >= n;
  if (dead) node0 = 0;
  float* Xw = X[wv];

  float h1[64];
#pragma unroll
  for (int f = 0; f < 64; ++f) h1[f] = benc[f];

  for (int kc = 0; kc < DINP; kc += 32) {
    // stage 64 rows x 32 cols (2 rows per load instruction, 128B segments)
#pragma unroll
    for (int r2 = 0; r2 < 32; ++r2) {
      int row = r2 * 2 + (lane >> 5);
      int col = lane & 31;
      int k = kc + col;
      long long nd = node0 + row;
      float v = 0.f;
      if (k < DIN && nd < n) v = inp[nd * DIN + k];
      Xw[row * 65 + col] = v;
    }
    // wave-private tile: intra-wave LDS ordering suffices, no __syncthreads
    float xr[32];
#pragma unroll
    for (int kk = 0; kk < 32; ++kk) xr[kk] = Xw[lane * 65 + kk];
    const float* wp = wenc + kc;
#pragma unroll
    for (int f = 0; f < 64; ++f) {
#pragma unroll
      for (int kk = 0; kk < 32; ++kk)
        h1[f] = fmaf(wp[f * DINP + kk], xr[kk], h1[f]);  // weight via s_load (uniform)
    }
  }

  // relu + transpose through LDS -> coalesced float4 stores
#pragma unroll
  for (int f = 0; f < 64; ++f) Xw[lane * 65 + f] = fmaxf(h1[f], 0.f);
  if (!dead) {
    long long maxg = ((long long)n - node0) * 64;
    float* ob = h1o + node0 * 64;
#pragma unroll
    for (int j = 0; j < 16; ++j) {
      int g = j * 256 + lane * 4;
      if (g < maxg) {
        int r = g >> 6, k = g & 63;
        float4 t;
        t.x = Xw[r * 65 + k + 0];
        t.y = Xw[r * 65 + k + 1];
        t.z = Xw[r * 65 + k + 2];
        t.w = Xw[r * 65 + k + 3];
        *(float4*)(ob + g) = t;
      }
    }
  }
}

// ---------- GRU: lane = node; x in regs, h in per-wave LDS, h2 in regs ----------
__global__ __launch_bounds__(256, 2) void k_gru(
    const float* __restrict__ h1g, const float* __restrict__ hid,
    const float* __restrict__ wih, const float* __restrict__ whh,
    const float* __restrict__ bih, const float* __restrict__ bhh,
    float* __restrict__ h2o, int n) {
  __shared__ float Hs[4][64 * 65];
  int tid = threadIdx.x;
  int wv = tid >> 6, lane = tid & 63;
  long long group = (long long)blockIdx.x * 4 + wv;
  long long node0 = group * 64;
  bool dead = node0 >= n;
  if (dead) node0 = 0;
  float* Hw = Hs[wv];
  long long maxg = ((long long)n - node0) * 64;

  // stage hid tile (coalesced 1KB/instr), layout Hw[r*65+k]
  const float* hbase = hid + node0 * 64;
#pragma unroll
  for (int j = 0; j < 16; ++j) {
    int g = j * 256 + lane * 4;
    float4 t = make_float4(0.f, 0.f, 0.f, 0.f);
    if (g < maxg) t = *(const float4*)(hbase + g);
    int r = g >> 6, k = g & 63;
    Hw[r * 65 + k + 0] = t.x;
    Hw[r * 65 + k + 1] = t.y;
    Hw[r * 65 + k + 2] = t.z;
    Hw[r * 65 + k + 3] = t.w;
  }

  // x = h1 row of this lane's node -> registers
  long long nodeL = node0 + lane;
  long long nodeC = (nodeL < n) ? nodeL : (long long)(n - 1);
  float xr[64];
  const float4* xp = (const float4*)(h1g + nodeC * 64);
#pragma unroll
  for (int q = 0; q < 16; ++q) {
    float4 t = xp[q];
    xr[q * 4 + 0] = t.x; xr[q * 4 + 1] = t.y;
    xr[q * 4 + 2] = t.z; xr[q * 4 + 3] = t.w;
  }

  float h2r[64];
  for (int f = 0; f < 64; ++f) {  // rolled: 6 live accumulators per f
    float ir = bih[f], iz = bih[64 + f], inn = bih[128 + f];
    float hrr = bhh[f], hz = bhh[64 + f], hn = bhh[128 + f];
    const float* wi0 = wih + f * 64;
    const float* wi1 = wih + (64 + f) * 64;
    const float* wi2 = wih + (128 + f) * 64;
    const float* wh0 = whh + f * 64;
    const float* wh1 = whh + (64 + f) * 64;
    const float* wh2 = whh + (128 + f) * 64;
#pragma unroll
    for (int k = 0; k < 64; ++k) {
      float a = xr[k];
      float b = Hw[lane * 65 + k];   // ds_read, overlaps VALU pipe
      ir  = fmaf(wi0[k], a, ir);
      iz  = fmaf(wi1[k], a, iz);
      inn = fmaf(wi2[k], a, inn);
      hrr = fmaf(wh0[k], b, hrr);
      hz  = fmaf(wh1[k], b, hz);
      hn  = fmaf(wh2[k], b, hn);
    }
    float r = 1.f / (1.f + __expf(-(ir + hrr)));
    float z = 1.f / (1.f + __expf(-(iz + hz)));
    float nn = tanhf(inn + r * hn);
    float hf = Hw[lane * 65 + f];
    h2r[f] = (1.f - z) * nn + z * hf;
  }

  // dump h2 into LDS, then coalesced float4 write-out
#pragma unroll
  for (int f = 0; f < 64; ++f) Hw[lane * 65 + f] = h2r[f];
  if (!dead) {
    float* ob = h2o + node0 * 64;
#pragma unroll
    for (int j = 0; j < 16; ++j) {
      int g = j * 256 + lane * 4;
      if (g < maxg) {
        int r = g >> 6, k = g & 63;
        float4 t;
        t.x = Hw[r * 65 + k + 0];
        t.y = Hw[r * 65 + k + 1];
        t.z = Hw[r * 65 + k + 2];
        t.w = Hw[r * 65 + k + 3];
        *(float4*)(ob + g) = t;
      }
    }
  }
}

// ---------- y = x @ W^T, W [64][64] row-major; thread = node ----------
__global__ void k_gemv64(const float* __restrict__ x, const float* __restrict__ W,
                         float* __restrict__ y, int n) {
  int node = blockIdx.x * 256 + threadIdx.x;
  if (node >= n) return;
  float xr[64];
  const float4* xp = (const float4*)(x + (size_t)node * 64);
#pragma unroll
  for (int q = 0; q < 16; ++q) {
    float4 t = xp[q];
    xr[q * 4 + 0] = t.x; xr[q * 4 + 1] = t.y;
    xr[q * 4 + 2] = t.z; xr[q * 4 + 3] = t.w;
  }
  float* yo = y + (size_t)node * 64;
#pragma unroll 4
  for (int f = 0; f < 64; ++f) {
    float acc = 0.f;
    const float* wr = W + f * 64;
#pragma unroll
    for (int k = 0; k < 64; ++k) acc = fmaf(wr[k], xr[k], acc);
    yo[f] = acc;
  }
}

// ---------- gather aggregation: wave = dst node, lane = feature ----------
__global__ void k_agg(const float* __restrict__ y, const int* __restrict__ row_start,
                      const int* __restrict__ csr, const float* __restrict__ dis,
                      const float* __restrict__ bias, float* __restrict__ out,
                      int n, int dorelu) {
  int t = blockIdx.x * 256 + threadIdx.x;
  int w = t >> 6;
  int lane = t & 63;
  if (w >= n) return;
  w = __builtin_amdgcn_readfirstlane(w);  // wave-uniform -> scalar path
  int beg = row_start[w], end = row_start[w + 1];
  float acc = 0.f;
  int i = beg;
  for (; i + 4 <= end; i += 4) {
    int s0 = csr[i], s1 = csr[i + 1], s2 = csr[i + 2], s3 = csr[i + 3];
    float n0 = dis[s0], n1 = dis[s1], n2 = dis[s2], n3 = dis[s3];
    float v0 = y[(size_t)s0 * 64 + lane];
    float v1 = y[(size_t)s1 * 64 + lane];
    float v2 = y[(size_t)s2 * 64 + lane];
    float v3 = y[(size_t)s3 * 64 + lane];
    acc += v0 * n0 + v1 * n1 + v2 * n2 + v3 * n3;
  }
  for (; i < end; ++i) {
    int s = csr[i];
    acc += y[(size_t)s * 64 + lane] * dis[s];
  }
  acc = acc * dis[w] + bias[lane];
  if (dorelu) acc = fmaxf(acc, 0.f);
  out[(size_t)w * 64 + lane] = acc;
}

// ---------- Q head ----------
__global__ void k_qhead(const float* __restrict__ h3, const float* __restrict__ qw,
                        const float* __restrict__ qb, float* __restrict__ qout, int n) {
  int node = blockIdx.x * 256 + threadIdx.x;
  if (node >= n) return;
  float xr[64];
  const float4* xp = (const float4*)(h3 + (size_t)node * 64);
#pragma unroll
  for (int q = 0; q < 16; ++q) {
    float4 t = xp[q];
    xr[q * 4 + 0] = t.x; xr[q * 4 + 1] = t.y;
    xr[q * 4 + 2] = t.z; xr[q * 4 + 3] = t.w;
  }
  float* qo = qout + (size_t)node * AHEAD;
#pragma unroll 2
  for (int a = 0; a < AHEAD; ++a) {
    float acc = qb[a];
    const float* wr = qw + a * 64;
#pragma unroll
    for (int k = 0; k < 64; ++k) acc = fmaf(wr[k], xr[k], acc);
    qo[a] = acc;
  }
}

extern "C" void kernel_launch(void* const* d_in, const int* in_sizes, int n_in,
                              void* d_out, int out_size, void* d_ws, size_t ws_size,
                              hipStream_t stream) {
  const float* inp  = (const float*)d_in[0];
  const float* hid  = (const float*)d_in[1];
  const int*   eidx = (const int*)d_in[2];
  const float* encw = (const float*)d_in[3];
  const float* encb = (const float*)d_in[4];
  const float* wih  = (const float*)d_in[5];
  const float* whh  = (const float*)d_in[6];
  const float* bih  = (const float*)d_in[7];
  const float* bhh  = (const float*)d_in[8];
  const float* g1w  = (const float*)d_in[9];
  const float* g1b  = (const float*)d_in[10];
  const float* g2w  = (const float*)d_in[11];
  const float* g2b  = (const float*)d_in[12];
  const float* qw   = (const float*)d_in[13];
  const float* qb   = (const float*)d_in[14];

  int n = in_sizes[1] / H;   // 200000
  int e = in_sizes[2] / 2;   // 3200000
  const int* esrc = eidx;
  const int* edst = eidx + e;

  float* qout = (float*)d_out;
  float* h2o  = (float*)d_out + (size_t)n * AHEAD;

  // workspace carve (~175 MB)
  char* w = (char*)d_ws;
  float* wencp   = (float*)w; w += (size_t)64 * DINP * 4;
  int* deg       = (int*)w;   w += (size_t)n * 4;
  int* part      = (int*)w;   w += (size_t)n * 4;
  int* bsums     = (int*)w;   w += 4096;
  int* row_start = (int*)w;   w += ((size_t)n + 1) * 4;
  int* cursor    = (int*)w;   w += (size_t)n * 4;
  float* dis     = (float*)w; w += (size_t)n * 4;
  int* csr       = (int*)w;   w += (size_t)(e + n) * 4;
  w = (char*)(((uintptr_t)w + 15) & ~(uintptr_t)15);
  float* h1buf   = (float*)w; w += (size_t)n * H * 4;
  float* ybuf    = (float*)w; w += (size_t)n * H * 4;
  float* xbuf    = (float*)w; w += (size_t)n * H * 4;

  int nb = (n + 255) / 256;
  int total = e + n;

  hipLaunchKernelGGL(k_pad_encw, dim3((64 * DINP + 255) / 256), dim3(256), 0, stream, encw, wencp);
  hipLaunchKernelGGL(k_init_deg, dim3(nb), dim3(256), 0, stream, deg, n);
  hipLaunchKernelGGL(k_deg, dim3((e + 255) / 256), dim3(256), 0, stream, edst, deg, e);
  hipLaunchKernelGGL(k_scan1, dim3(nb), dim3(256), 0, stream, deg, part, bsums, n);
  hipLaunchKernelGGL(k_scan2, dim3(1), dim3(1024), 0, stream, bsums, nb);
  hipLaunchKernelGGL(k_scanfin, dim3((n + 1 + 255) / 256), dim3(256), 0, stream,
                     part, bsums, deg, row_start, cursor, dis, n, total);
  hipLaunchKernelGGL(k_fill, dim3((total + 255) / 256), dim3(256), 0, stream,
                     esrc, edst, cursor, csr, e, n);

  int groups = (n + 63) / 64;
  int gblocks = (groups + 3) / 4;
  hipLaunchKernelGGL(k_enc, dim3(gblocks), dim3(256), 0, stream,
                     inp, wencp, encb, h1buf, n);
  hipLaunchKernelGGL(k_gru, dim3(gblocks), dim3(256), 0, stream,
                     h1buf, hid, wih, whh, bih, bhh, h2o, n);

  int aggblocks = (int)(((size_t)n * 64 + 255) / 256);
  hipLaunchKernelGGL(k_gemv64, dim3(nb), dim3(256), 0, stream, h2o, g1w, ybuf, n);
  hipLaunchKernelGGL(k_agg, dim3(aggblocks), dim3(256), 0, stream,
                     ybuf, row_start, csr, dis, g1b, xbuf, n, 1);
  hipLaunchKernelGGL(k_gemv64, dim3(nb), dim3(256), 0, stream, xbuf, g2w, ybuf, n);
  hipLaunchKernelGGL(k_agg, dim3(aggblocks), dim3(256), 0, stream,
                     ybuf, row_start, csr, dis, g2b, xbuf, n, 0);
  hipLaunchKernelGGL(k_qhead, dim3(nb), dim3(256), 0, stream, xbuf, qw, qb, qout, n);
}